// Round 8
// baseline (159.428 us; speedup 1.0000x reference)
//
#include <hip/hip_runtime.h>
#include <hip/hip_bf16.h>
#include <math.h>

#define EPSF 1e-6f

// clang native vector type — required by __builtin_nontemporal_load
typedef float float4n __attribute__((ext_vector_type(4)));

__device__ inline float readlane_f(float v, int l) {
    return __int_as_float(__builtin_amdgcn_readlane(__float_as_int(v), l));
}

// ---------------------------------------------------------------------------
// Kernel A: half-bucket partial means. One WAVE per (tensor, bh, bucket, half):
// 8192 waves -> 2048 blocks x 256. No LDS, no barriers.
// Each wave: 16 nt float4 loads/lane covering 64 rows, shfl_xor(16,32) reduce,
// writes sum/128 to ws[t][bh][half][bucket][dim]. Halves are summed in kernel
// B's staging (partial-mean combine), so no cross-wave communication here.
// ---------------------------------------------------------------------------
__global__ __launch_bounds__(256) void bucket_mean_kernel(
    const float* __restrict__ q,
    const float* __restrict__ k,
    float* __restrict__ sqk)  // [2][32][2][64][64]
{
    int g    = blockIdx.x * 4 + (threadIdx.x >> 6);  // 0..8191
    int part = g & 1;
    int g2   = g >> 1;
    int t      = g2 >> 11;       // 0 = q, 1 = k
    int bh     = (g2 >> 6) & 31;
    int bucket = g2 & 63;

    const float* src = t ? k : q;
    const float4n* base = reinterpret_cast<const float4n*>(
        src + ((size_t)bh * 8192 + (size_t)bucket * 128 + part * 64) * 64);

    int lane = threadIdx.x & 63;
    int rr   = lane >> 4;        // 0..3
    int c    = lane & 15;        // 0..15

    float4n v[16];
    #pragma unroll
    for (int u = 0; u < 16; ++u)
        v[u] = __builtin_nontemporal_load(&base[(rr + u * 4) * 16 + c]);
    float4n acc = (float4n)(0.f);
    #pragma unroll
    for (int u = 0; u < 16; ++u)
        acc += v[u];

    // reduce across the 4 row groups (lane bits 4,5)
    acc.x += __shfl_xor(acc.x, 16, 64);
    acc.y += __shfl_xor(acc.y, 16, 64);
    acc.z += __shfl_xor(acc.z, 16, 64);
    acc.w += __shfl_xor(acc.w, 16, 64);
    acc.x += __shfl_xor(acc.x, 32, 64);
    acc.y += __shfl_xor(acc.y, 32, 64);
    acc.z += __shfl_xor(acc.z, 32, 64);
    acc.w += __shfl_xor(acc.w, 32, 64);

    if (lane < 16) {
        acc *= (1.0f / 128.0f);   // half-sum / 128; other half adds to full mean
        float4n* dst = reinterpret_cast<float4n*>(
            sqk + ((((size_t)t * 32 + bh) * 2 + part) * 64 + bucket) * 64);
        dst[c] = acc;
    }
}

// ---------------------------------------------------------------------------
// Kernel B: per-bh  R = sq·sk^T/8, gumbel perturb, 8 sinkhorn iters, exp.
// grid.x = 32 (one block per bh), block = 1024 threads.
// Staging combines the two half-bucket partials (elementwise add).
// Dot phase: sq rows in registers, broadcast via v_readlane; sk from LDS.
// ---------------------------------------------------------------------------
__global__ __launch_bounds__(1024) void sinkhorn_kernel(
    const float* __restrict__ sqk,      // [2][32][2][64][64]
    const float* __restrict__ u_gumbel, // [32][64][64]
    float* __restrict__ out)            // [32][64][64]
{
    int bh  = blockIdx.x;
    int tid = threadIdx.x;

    __shared__ float sk_s[64][65];
    __shared__ float r_s[64][65];

    const float* sqp = sqk + (size_t)bh * 8192;                    // t=0, parts 0/1
    const float* skp = sqk + (size_t)32 * 8192 + (size_t)bh * 8192; // t=1

    // stage sk into LDS, combining halves (4096 elems / 1024 threads)
    #pragma unroll
    for (int t = 0; t < 4; ++t) {
        int idx = tid + 1024 * t;
        sk_s[idx >> 6][idx & 63] = skp[idx] + skp[4096 + idx];
    }

    int lane = tid & 63;
    int i0   = tid >> 6;              // wave id 0..15 (uniform per wave)

    // sq rows for this wave, in registers: lane e holds sq[i][e]
    float sqr0 = sqp[(i0     ) * 64 + lane] + sqp[4096 + (i0     ) * 64 + lane];
    float sqr1 = sqp[(i0 + 16) * 64 + lane] + sqp[4096 + (i0 + 16) * 64 + lane];
    float sqr2 = sqp[(i0 + 32) * 64 + lane] + sqp[4096 + (i0 + 32) * 64 + lane];
    float sqr3 = sqp[(i0 + 48) * 64 + lane] + sqp[4096 + (i0 + 48) * 64 + lane];
    __syncthreads();

    {
        int j = lane;
        float acc0 = 0.f, acc1 = 0.f, acc2 = 0.f, acc3 = 0.f;
        #pragma unroll
        for (int e = 0; e < 64; ++e) {
            float s = sk_s[j][e];     // banks (j+e)%32: 2-way, free
            acc0 = fmaf(readlane_f(sqr0, e), s, acc0);
            acc1 = fmaf(readlane_f(sqr1, e), s, acc1);
            acc2 = fmaf(readlane_f(sqr2, e), s, acc2);
            acc3 = fmaf(readlane_f(sqr3, e), s, acc3);
        }
        const float scale = 0.125f;   // 64^-0.5
        const float invT  = 1.0f / 0.7f;
        float accs[4] = {acc0, acc1, acc2, acc3};
        #pragma unroll
        for (int t = 0; t < 4; ++t) {
            int i   = i0 + 16 * t;
            float R = accs[t] * scale;
            float rl = fmaxf(R, 0.f);
            float u  = u_gumbel[(size_t)bh * 4096 + i * 64 + j];
            float gm = -__logf(-__logf(u + EPSF) + EPSF);
            r_s[i][j] = (__logf(rl + EPSF) + gm) * invT;
        }
    }
    __syncthreads();

    // Sinkhorn: 8 x (LSE-normalize axis=2 rows, then axis=1 cols).
    int lane16 = tid & 15;
    int rc     = tid >> 4;            // 0..63
    int cbase  = lane16 * 4;
    for (int it = 0; it < 8; ++it) {
        {   // axis=2: LSE over j within row rc
            float v0 = r_s[rc][cbase + 0], v1 = r_s[rc][cbase + 1];
            float v2 = r_s[rc][cbase + 2], v3 = r_s[rc][cbase + 3];
            float m = fmaxf(fmaxf(v0, v1), fmaxf(v2, v3));
            m = fmaxf(m, __shfl_xor(m, 1, 64));
            m = fmaxf(m, __shfl_xor(m, 2, 64));
            m = fmaxf(m, __shfl_xor(m, 4, 64));
            m = fmaxf(m, __shfl_xor(m, 8, 64));
            float s = __expf(v0 - m) + __expf(v1 - m)
                    + __expf(v2 - m) + __expf(v3 - m);
            s += __shfl_xor(s, 1, 64);
            s += __shfl_xor(s, 2, 64);
            s += __shfl_xor(s, 4, 64);
            s += __shfl_xor(s, 8, 64);
            float lse = m + __logf(s);
            r_s[rc][cbase + 0] = v0 - lse;
            r_s[rc][cbase + 1] = v1 - lse;
            r_s[rc][cbase + 2] = v2 - lse;
            r_s[rc][cbase + 3] = v3 - lse;
        }
        __syncthreads();
        {   // axis=1: LSE over i within column rc
            float v0 = r_s[cbase + 0][rc], v1 = r_s[cbase + 1][rc];
            float v2 = r_s[cbase + 2][rc], v3 = r_s[cbase + 3][rc];
            float m = fmaxf(fmaxf(v0, v1), fmaxf(v2, v3));
            m = fmaxf(m, __shfl_xor(m, 1, 64));
            m = fmaxf(m, __shfl_xor(m, 2, 64));
            m = fmaxf(m, __shfl_xor(m, 4, 64));
            m = fmaxf(m, __shfl_xor(m, 8, 64));
            float s = __expf(v0 - m) + __expf(v1 - m)
                    + __expf(v2 - m) + __expf(v3 - m);
            s += __shfl_xor(s, 1, 64);
            s += __shfl_xor(s, 2, 64);
            s += __shfl_xor(s, 4, 64);
            s += __shfl_xor(s, 8, 64);
            float lse = m + __logf(s);
            r_s[cbase + 0][rc] = v0 - lse;
            r_s[cbase + 1][rc] = v1 - lse;
            r_s[cbase + 2][rc] = v2 - lse;
            r_s[cbase + 3][rc] = v3 - lse;
        }
        __syncthreads();
    }

    // out = exp(r)
    #pragma unroll
    for (int t = 0; t < 4; ++t) {
        int idx = tid + 1024 * t;
        out[(size_t)bh * 4096 + idx] = __expf(r_s[idx >> 6][idx & 63]);
    }
}

extern "C" void kernel_launch(void* const* d_in, const int* in_sizes, int n_in,
                              void* d_out, int out_size, void* d_ws, size_t ws_size,
                              hipStream_t stream) {
    const float* q = (const float*)d_in[0];        // [32,8192,64]
    const float* k = (const float*)d_in[1];        // [32,8192,64]
    const float* u = (const float*)d_in[2];        // [32,64,64]
    float* out = (float*)d_out;                    // [32,64,64]
    float* sqk = (float*)d_ws;                     // [2][32][2][64][64] = 2 MiB

    bucket_mean_kernel<<<2048, 256, 0, stream>>>(q, k, sqk);
    sinkhorn_kernel<<<32, 1024, 0, stream>>>(sqk, u, out);
}